// Round 1
// baseline (118.548 us; speedup 1.0000x reference)
//
#include <hip/hip_runtime.h>

#define DIM   512
#define RANK  64
#define TDIM  1024
#define BB    2
#define NROWS (BB * TDIM)   // 2048 flattened rows per tensor

typedef float v4f __attribute__((ext_vector_type(4)));

__device__ __forceinline__ float fast_exp2(float x) { return __builtin_amdgcn_exp2f(x); }
__device__ __forceinline__ float fast_rcp(float x)  { return __builtin_amdgcn_rcpf(x); }

// ---------------------------------------------------------------------------
// Projection v2: full-K per block. No split-K, no atomics, no memset.
// grid = (NROWS/32, 1, 2) = 128 blocks, 256 threads. Tile 32 rows x 64 r,
// micro 2x4 per thread. K=512 streamed in 64-wide chunks through
// double-buffered LDS (51 KB). Global prefetch issued before compute so
// HBM latency hides under the FMA chunk (~1k cycles).
// Per-chunk per-wave: 96 ds_read_b128 (~1150 cyc) vs 512 FMA-cyc -> ~4 us.
// ---------------------------------------------------------------------------
__global__ __launch_bounds__(256)
void proj_kernel(const float* __restrict__ tv, const float* __restrict__ sv,
                 const float* __restrict__ Wt, const float* __restrict__ Ws,
                 float* __restrict__ pt, float* __restrict__ ps)
{
    const int which = blockIdx.z;
    const float* X = which ? sv : tv;
    const float* W = which ? Ws : Wt;
    float* P       = which ? ps : pt;

    const int row0 = blockIdx.x * 32;
    const int tid  = threadIdx.x;
    const int tx   = tid & 15;
    const int ty   = tid >> 4;

    __shared__ float xs[2][32][68];
    __shared__ float wsm[2][64][68];

    const int lr = tid >> 4;        // loader row 0..15
    const int lc = (tid & 15) * 4;  // loader col 0..60

    // prefetch chunk 0 into buffer 0
#pragma unroll
    for (int p = 0; p < 2; p++)
        *(v4f*)&xs[0][lr + 16 * p][lc] =
            *(const v4f*)&X[(size_t)(row0 + lr + 16 * p) * DIM + lc];
#pragma unroll
    for (int p = 0; p < 4; p++)
        *(v4f*)&wsm[0][lr + 16 * p][lc] =
            *(const v4f*)&W[(size_t)(lr + 16 * p) * DIM + lc];
    __syncthreads();

    float acc[2][4];
#pragma unroll
    for (int i = 0; i < 2; i++)
#pragma unroll
        for (int j = 0; j < 4; j++) acc[i][j] = 0.f;

    int buf = 0;
    for (int kc = 0; kc < DIM; kc += 64) {
        // issue next chunk's global loads early (drain under compute)
        v4f xpre[2], wpre[4];
        const bool more = (kc + 64) < DIM;
        if (more) {
            const int koff = kc + 64 + lc;
#pragma unroll
            for (int p = 0; p < 2; p++)
                xpre[p] = *(const v4f*)&X[(size_t)(row0 + lr + 16 * p) * DIM + koff];
#pragma unroll
            for (int p = 0; p < 4; p++)
                wpre[p] = *(const v4f*)&W[(size_t)(lr + 16 * p) * DIM + koff];
        }

#pragma unroll 2
        for (int k4 = 0; k4 < 64; k4 += 4) {
            v4f a[2], b[4];
#pragma unroll
            for (int i = 0; i < 2; i++)
                a[i] = *(const v4f*)&xs[buf][ty + 16 * i][k4];   // broadcast per 16-group
#pragma unroll
            for (int j = 0; j < 4; j++)
                b[j] = *(const v4f*)&wsm[buf][tx + 16 * j][k4];  // 2-way bank: free
#pragma unroll
            for (int i = 0; i < 2; i++)
#pragma unroll
                for (int j = 0; j < 4; j++) {
                    acc[i][j] = fmaf(a[i].x, b[j].x, acc[i][j]);
                    acc[i][j] = fmaf(a[i].y, b[j].y, acc[i][j]);
                    acc[i][j] = fmaf(a[i].z, b[j].z, acc[i][j]);
                    acc[i][j] = fmaf(a[i].w, b[j].w, acc[i][j]);
                }
        }

        if (more) {
            const int nxt = buf ^ 1;
#pragma unroll
            for (int p = 0; p < 2; p++) *(v4f*)&xs[nxt][lr + 16 * p][lc] = xpre[p];
#pragma unroll
            for (int p = 0; p < 4; p++) *(v4f*)&wsm[nxt][lr + 16 * p][lc] = wpre[p];
        }
        __syncthreads();   // next iteration reads nxt; prev buffer reads retired
        buf ^= 1;
    }

#pragma unroll
    for (int i = 0; i < 2; i++)
#pragma unroll
        for (int j = 0; j < 4; j++)
            P[(size_t)(row0 + ty + 16 * i) * RANK + tx + 16 * j] = acc[i][j];
}

// ---------------------------------------------------------------------------
// Pairwise: out[b][t][s] = sum_r iw[r]*silu(pt[b,t,r]*ps[b,s,r])
//                          + tl[b,t] + sl[b,s] + bias
// grid = (16, 32, 2) = 1024 blocks (4/CU, 16 waves/CU). Tile 32(t) x 64(s),
// micro 2x4 per thread.
// Paired-reciprocal: for elements (k, k+1) share one rcp:
//   r = rcp(d0*d1); sig0 = r*d1; sig1 = r*d0   (exact algebra)
// Per element: trans pipe 12 cyc (1 exp + 0.5 rcp), VALU 11 cyc.
// UNCHANGED this round (attribution: proj restructure only).
// ---------------------------------------------------------------------------
__global__ __launch_bounds__(256)
void pair_kernel(const float* __restrict__ pt, const float* __restrict__ ps,
                 const float* __restrict__ wt_out, const float* __restrict__ ws_out,
                 const float* __restrict__ iw, const float* __restrict__ bias_p,
                 float* __restrict__ out)
{
    const int b  = blockIdx.z;
    const int t0 = blockIdx.y * 32;
    const int s0 = blockIdx.x * 64;
    const int tid = threadIdx.x;
    const int tx  = tid & 15;
    const int ty  = tid >> 4;

    __shared__ float pts[32][68];
    __shared__ float sts[64][68];
    __shared__ __align__(16) float wsh[64];
    __shared__ float tlsh[32];
    __shared__ float slsh[64];

    const float* ptb = pt + ((size_t)b * TDIM + t0) * RANK;
    const float* psb = ps + ((size_t)b * TDIM + s0) * RANK;

#pragma unroll
    for (int p = 0; p < 2; p++) {
        const int r = (tid >> 4) + p * 16;
        const int c = (tid & 15) * 4;
        *(v4f*)&pts[r][c] = *(const v4f*)&ptb[(size_t)r * RANK + c];
    }
#pragma unroll
    for (int p = 0; p < 4; p++) {
        const int r = (tid >> 4) + p * 16;
        const int c = (tid & 15) * 4;
        *(v4f*)&sts[r][c] = *(const v4f*)&psb[(size_t)r * RANK + c];
    }
    if (tid < 64) wsh[tid] = iw[tid];
    __syncthreads();

    // per-block linear terms
    if (tid < 32) {
        float v = 0.f;
#pragma unroll 8
        for (int r = 0; r < RANK; r++) v = fmaf(pts[tid][r], wt_out[r], v);
        tlsh[tid] = v;
    } else if (tid >= 64 && tid < 128) {
        const int s = tid - 64;
        float v = 0.f;
#pragma unroll 8
        for (int r = 0; r < RANK; r++) v = fmaf(sts[s][r], ws_out[r], v);
        slsh[s] = v;
    }
    __syncthreads();

    const float bias = bias_p[0];
    const float NL2E = -1.44269504088896340736f;  // -log2(e)

    float acc[2][4];
#pragma unroll
    for (int i = 0; i < 2; i++)
#pragma unroll
        for (int j = 0; j < 4; j++) acc[i][j] = 0.f;

    for (int r4 = 0; r4 < RANK; r4 += 4) {
        const v4f wv4 = *(const v4f*)&wsh[r4];
        const float wv[4] = {wv4.x, wv4.y, wv4.z, wv4.w};

        float a2[2][4], wa[2][4], bv[4][4];
#pragma unroll
        for (int i = 0; i < 2; i++) {
            const v4f av = *(const v4f*)&pts[ty + 16 * i][r4];   // broadcast per 16-group
            const float avv[4] = {av.x, av.y, av.z, av.w};
#pragma unroll
            for (int k = 0; k < 4; k++) {
                a2[i][k] = avv[k] * NL2E;   // feeds exp2
                wa[i][k] = avv[k] * wv[k];  // feeds w*z
            }
        }
#pragma unroll
        for (int j = 0; j < 4; j++) {
            const v4f bb = *(const v4f*)&sts[tx + 16 * j][r4];   // 2-way bank: free
            bv[j][0] = bb.x; bv[j][1] = bb.y; bv[j][2] = bb.z; bv[j][3] = bb.w;
        }

#pragma unroll
        for (int i = 0; i < 2; i++)
#pragma unroll
            for (int j = 0; j < 4; j++)
#pragma unroll
                for (int k2 = 0; k2 < 4; k2 += 2) {
                    const float t0v = a2[i][k2]     * bv[j][k2];
                    const float t1v = a2[i][k2 + 1] * bv[j][k2 + 1];
                    const float e0  = fast_exp2(t0v);            // exp(-z0)
                    const float e1  = fast_exp2(t1v);            // exp(-z1)
                    const float d0  = e0 + 1.0f;
                    const float d1  = e1 + 1.0f;
                    const float r   = fast_rcp(d0 * d1);         // shared reciprocal
                    const float s0  = r * d1;                    // sigmoid(z0)
                    const float s1  = r * d0;                    // sigmoid(z1)
                    const float wz0 = wa[i][k2]     * bv[j][k2];
                    const float wz1 = wa[i][k2 + 1] * bv[j][k2 + 1];
                    acc[i][j] = fmaf(wz0, s0, acc[i][j]);
                    acc[i][j] = fmaf(wz1, s1, acc[i][j]);
                }
    }

    // epilogue
#pragma unroll
    for (int i = 0; i < 2; i++) {
        const int t = t0 + ty + 16 * i;
        const float tl = tlsh[ty + 16 * i];
        float* orow = out + ((size_t)b * TDIM + t) * TDIM + s0;
#pragma unroll
        for (int j = 0; j < 4; j++) {
            orow[tx + 16 * j] = acc[i][j] + tl + slsh[tx + 16 * j] + bias;
        }
    }
}

// ---------------------------------------------------------------------------
extern "C" void kernel_launch(void* const* d_in, const int* in_sizes, int n_in,
                              void* d_out, int out_size, void* d_ws, size_t ws_size,
                              hipStream_t stream)
{
    const float* tv     = (const float*)d_in[0];  // [2,1024,512]
    const float* sv     = (const float*)d_in[1];  // [2,1024,512]
    const float* Wt     = (const float*)d_in[2];  // [64,512]
    const float* Ws     = (const float*)d_in[3];  // [64,512]
    const float* wt_out = (const float*)d_in[4];  // [64]
    const float* ws_out = (const float*)d_in[5];  // [64]
    const float* iw     = (const float*)d_in[6];  // [64]
    const float* bias   = (const float*)d_in[7];  // scalar
    float* out = (float*)d_out;                   // [2,1024,1024]

    float* pt = (float*)d_ws;                          // [2048][64]
    float* ps = pt + (size_t)NROWS * RANK;             // [2048][64]

    // no memset needed: proj writes every element exactly once (no split-K)
    dim3 pgrid(NROWS / 32, 1, 2);
    proj_kernel<<<pgrid, 256, 0, stream>>>(tv, sv, Wt, Ws, pt, ps);

    dim3 ggrid(TDIM / 64, TDIM / 32, BB);
    pair_kernel<<<ggrid, 256, 0, stream>>>(pt, ps, wt_out, ws_out, iw, bias, out);
}

// Round 2
// 112.110 us; speedup vs baseline: 1.0574x; 1.0574x over previous
//
#include <hip/hip_runtime.h>

#define DIM    512
#define RANK   64
#define TDIM   1024
#define BB     2
#define NROWS  (BB * TDIM)     // 2048 flattened rows per tensor
#define KSPLIT 4
#define KCH    (DIM / KSPLIT)  // 128 K-columns per proj block

typedef float v4f __attribute__((ext_vector_type(4)));
typedef float v2f __attribute__((ext_vector_type(2)));

__device__ __forceinline__ float fast_exp2(float x) { return __builtin_amdgcn_exp2f(x); }
__device__ __forceinline__ float fast_rcp(float x)  { return __builtin_amdgcn_rcpf(x); }

// ---------------------------------------------------------------------------
// Projection v3: split-K=4 into 4 SEPARATE buffers (no atomics, no memset).
// grid = (NROWS/32, KSPLIT, 2) = 512 blocks (2/CU, 8 waves/CU).
// Tile 32 rows x 64 ranks, K=128 per block, single LDS fill (50.7 KB:
// stride 132 words = 528 B -> 16B-aligned rows, bank offset 4 -> 2-way free).
// RANK-SLOT PERMUTATION: thread (tx,ty) computes logical ranks {tx+16j},
// stores them at slots {4tx+j} so the output store is one v4f per row.
// pair_kernel consumes the same permutation (sum over r is perm-invariant)
// by permuting iw/wt_out/ws_out at load: logical(c) = (c>>2) + 16*(c&3).
// ---------------------------------------------------------------------------
__global__ __launch_bounds__(256)
void proj_kernel(const float* __restrict__ tv, const float* __restrict__ sv,
                 const float* __restrict__ Wt, const float* __restrict__ Ws,
                 float* __restrict__ pt, float* __restrict__ ps)
{
    const int which = blockIdx.z;
    const float* X = which ? sv : tv;
    const float* W = which ? Ws : Wt;
    float* P = (which ? ps : pt) + (size_t)blockIdx.y * NROWS * RANK;

    const int row0 = blockIdx.x * 32;
    const int kc   = blockIdx.y * KCH;
    const int tid  = threadIdx.x;
    const int tx   = tid & 15;
    const int ty   = tid >> 4;

    __shared__ float xs[32][132];   // 16.9 KB
    __shared__ float wsm[64][132];  // 33.8 KB

    // ---- stage X tile: 32 rows x 128 cols = 1024 v4f, 4 per thread ----
#pragma unroll
    for (int p = 0; p < 4; p++) {
        const int li = p * 256 + tid;     // 0..1023
        const int r  = li >> 5;           // 0..31
        const int c  = (li & 31) << 2;    // 0..124
        *(v4f*)&xs[r][c] = *(const v4f*)&X[(size_t)(row0 + r) * DIM + kc + c];
    }
    // ---- stage W tile: 64 ranks x 128 cols = 2048 v4f, 8 per thread ----
#pragma unroll
    for (int p = 0; p < 8; p++) {
        const int li = p * 256 + tid;     // 0..2047
        const int r  = li >> 5;           // 0..63
        const int c  = (li & 31) << 2;
        *(v4f*)&wsm[r][c] = *(const v4f*)&W[(size_t)r * DIM + kc + c];
    }
    __syncthreads();

    float acc[2][4];
#pragma unroll
    for (int i = 0; i < 2; i++)
#pragma unroll
        for (int j = 0; j < 4; j++) acc[i][j] = 0.f;

#pragma unroll 4
    for (int k4 = 0; k4 < KCH; k4 += 4) {
        v4f a[2], b[4];
#pragma unroll
        for (int i = 0; i < 2; i++)
            a[i] = *(const v4f*)&xs[ty + 16 * i][k4];   // broadcast per 16-group
#pragma unroll
        for (int j = 0; j < 4; j++)
            b[j] = *(const v4f*)&wsm[tx + 16 * j][k4];  // 2-way bank: free
#pragma unroll
        for (int i = 0; i < 2; i++)
#pragma unroll
            for (int j = 0; j < 4; j++) {
                acc[i][j] = fmaf(a[i].x, b[j].x, acc[i][j]);
                acc[i][j] = fmaf(a[i].y, b[j].y, acc[i][j]);
                acc[i][j] = fmaf(a[i].z, b[j].z, acc[i][j]);
                acc[i][j] = fmaf(a[i].w, b[j].w, acc[i][j]);
            }
    }

    // slot-permuted vector store: slots 4tx..4tx+3 hold logical ranks tx+16j
#pragma unroll
    for (int i = 0; i < 2; i++) {
        v4f o = {acc[i][0], acc[i][1], acc[i][2], acc[i][3]};
        *(v4f*)&P[(size_t)(row0 + ty + 16 * i) * RANK + tx * 4] = o;
    }
}

// ---------------------------------------------------------------------------
// Pairwise: out[b][t][s] = sum_r iw[r]*silu(pt[b,t,r]*ps[b,s,r])
//                          + tl[b,t] + sl[b,s] + bias
// grid = (16, 32, 2) = 1024 blocks (4/CU). Tile 32(t) x 64(s), micro 2x4.
// Prologue sums the 4 K-split buffers; weight vectors loaded PERMUTED to
// match proj's rank-slot layout.
// Inner loop: packed-f32 (v_pk_*_f32) + 4-way shared reciprocal:
//   r = rcp(d0*d1*d2*d3); sig_k recovered via partial products (exact).
// Per 4 elems: 6 pk + 11 scalar VALU + 5 trans (vs 22 VALU + 6 trans before).
// ---------------------------------------------------------------------------
__global__ __launch_bounds__(256)
void pair_kernel(const float* __restrict__ pt, const float* __restrict__ ps,
                 const float* __restrict__ wt_out, const float* __restrict__ ws_out,
                 const float* __restrict__ iw, const float* __restrict__ bias_p,
                 float* __restrict__ out)
{
    const int b  = blockIdx.z;
    const int t0 = blockIdx.y * 32;
    const int s0 = blockIdx.x * 64;
    const int tid = threadIdx.x;
    const int tx  = tid & 15;
    const int ty  = tid >> 4;

    __shared__ float pts[32][68];
    __shared__ float sts[64][68];
    __shared__ __align__(16) float wsh[64];   // iw, slot-permuted
    __shared__ float wtsh[64];                // wt_out, slot-permuted
    __shared__ float wssh[64];                // ws_out, slot-permuted
    __shared__ float tlsh[32];
    __shared__ float slsh[64];

    const size_t SPL = (size_t)NROWS * RANK;
    const float* ptb = pt + ((size_t)b * TDIM + t0) * RANK;
    const float* psb = ps + ((size_t)b * TDIM + s0) * RANK;

    // ---- stage pt rows (sum 4 K-splits): 32 rows x 16 v4f -> 2/thread ----
#pragma unroll
    for (int p = 0; p < 2; p++) {
        const int li = p * 256 + tid;
        const int r  = li >> 4;
        const int c  = (li & 15) << 2;
        const float* src = ptb + (size_t)r * RANK + c;
        v4f v = *(const v4f*)src;
        v += *(const v4f*)(src + SPL);
        v += *(const v4f*)(src + 2 * SPL);
        v += *(const v4f*)(src + 3 * SPL);
        *(v4f*)&pts[r][c] = v;
    }
    // ---- stage ps rows: 64 rows x 16 v4f -> 4/thread ----
#pragma unroll
    for (int p = 0; p < 4; p++) {
        const int li = p * 256 + tid;
        const int r  = li >> 4;
        const int c  = (li & 15) << 2;
        const float* src = psb + (size_t)r * RANK + c;
        v4f v = *(const v4f*)src;
        v += *(const v4f*)(src + SPL);
        v += *(const v4f*)(src + 2 * SPL);
        v += *(const v4f*)(src + 3 * SPL);
        *(v4f*)&sts[r][c] = v;
    }
    if (tid < 64) {
        const int lg = (tid >> 2) + 16 * (tid & 3);  // logical rank of slot tid
        wsh[tid]  = iw[lg];
        wtsh[tid] = wt_out[lg];
        wssh[tid] = ws_out[lg];
    }
    __syncthreads();

    // per-block linear terms (slot-space dot with permuted weights)
    if (tid < 32) {
        float v = 0.f;
#pragma unroll 8
        for (int r = 0; r < RANK; r++) v = fmaf(pts[tid][r], wtsh[r], v);
        tlsh[tid] = v;
    } else if (tid >= 64 && tid < 128) {
        const int s = tid - 64;
        float v = 0.f;
#pragma unroll 8
        for (int r = 0; r < RANK; r++) v = fmaf(sts[s][r], wssh[r], v);
        slsh[s] = v;
    }
    __syncthreads();

    const float bias = bias_p[0];
    const float NL2E = -1.44269504088896340736f;  // -log2(e)

    float acc[2][4];
#pragma unroll
    for (int i = 0; i < 2; i++)
#pragma unroll
        for (int j = 0; j < 4; j++) acc[i][j] = 0.f;

    for (int r4 = 0; r4 < RANK; r4 += 4) {
        const v4f wv4 = *(const v4f*)&wsh[r4];
        const v2f wvA = {wv4.x, wv4.y};
        const v2f wvB = {wv4.z, wv4.w};

        v2f a2[2][2], wa[2][2];
#pragma unroll
        for (int i = 0; i < 2; i++) {
            const v4f av = *(const v4f*)&pts[ty + 16 * i][r4];  // broadcast
            const v2f aA = {av.x, av.y};
            const v2f aB = {av.z, av.w};
            a2[i][0] = aA * NL2E;   // feeds exp2
            a2[i][1] = aB * NL2E;
            wa[i][0] = aA * wvA;    // feeds w*z
            wa[i][1] = aB * wvB;
        }
        v2f bv[4][2];
#pragma unroll
        for (int j = 0; j < 4; j++) {
            const v4f bb = *(const v4f*)&sts[tx + 16 * j][r4];  // 2-way bank: free
            bv[j][0] = (v2f){bb.x, bb.y};
            bv[j][1] = (v2f){bb.z, bb.w};
        }

#pragma unroll
        for (int i = 0; i < 2; i++)
#pragma unroll
            for (int j = 0; j < 4; j++) {
                const v2f tA = a2[i][0] * bv[j][0];     // pk_mul
                const v2f tB = a2[i][1] * bv[j][1];
                const float e0 = fast_exp2(tA.x);
                const float e1 = fast_exp2(tA.y);
                const float e2 = fast_exp2(tB.x);
                const float e3 = fast_exp2(tB.y);
                v2f dA = {e0, e1};  dA += 1.0f;          // pk_add
                v2f dB = {e2, e3};  dB += 1.0f;
                const float pA = dA.x * dA.y;
                const float pB = dB.x * dB.y;
                const float r  = fast_rcp(pA * pB);      // one rcp / 4 elems
                const v2f nA = wa[i][0] * bv[j][0];      // pk_mul
                const v2f nB = wa[i][1] * bv[j][1];
                const float uA = fmaf(nA.y, dA.x, nA.x * dA.y);
                const float uB = fmaf(nB.y, dB.x, nB.x * dB.y);
                const float rA = r * pB;                 // = 1/(d0*d1)
                const float rB = r * pA;                 // = 1/(d2*d3)
                acc[i][j] = fmaf(rA, uA, acc[i][j]);
                acc[i][j] = fmaf(rB, uB, acc[i][j]);
            }
    }

    // epilogue
#pragma unroll
    for (int i = 0; i < 2; i++) {
        const int t = t0 + ty + 16 * i;
        const float tl = tlsh[ty + 16 * i];
        float* orow = out + ((size_t)b * TDIM + t) * TDIM + s0;
#pragma unroll
        for (int j = 0; j < 4; j++) {
            orow[tx + 16 * j] = acc[i][j] + tl + slsh[tx + 16 * j] + bias;
        }
    }
}

// ---------------------------------------------------------------------------
extern "C" void kernel_launch(void* const* d_in, const int* in_sizes, int n_in,
                              void* d_out, int out_size, void* d_ws, size_t ws_size,
                              hipStream_t stream)
{
    const float* tv     = (const float*)d_in[0];  // [2,1024,512]
    const float* sv     = (const float*)d_in[1];  // [2,1024,512]
    const float* Wt     = (const float*)d_in[2];  // [64,512]
    const float* Ws     = (const float*)d_in[3];  // [64,512]
    const float* wt_out = (const float*)d_in[4];  // [64]
    const float* ws_out = (const float*)d_in[5];  // [64]
    const float* iw     = (const float*)d_in[6];  // [64]
    const float* bias   = (const float*)d_in[7];  // scalar
    float* out = (float*)d_out;                   // [2,1024,1024]

    const size_t SPL = (size_t)NROWS * RANK;      // 131072 floats
    float* pt = (float*)d_ws;                     // [KSPLIT][2048][64]
    float* ps = pt + (size_t)KSPLIT * SPL;        // [KSPLIT][2048][64]

    // no memset: every split slot is written exactly once
    dim3 pgrid(NROWS / 32, KSPLIT, 2);            // 512 blocks
    proj_kernel<<<pgrid, 256, 0, stream>>>(tv, sv, Wt, Ws, pt, ps);

    dim3 ggrid(TDIM / 64, TDIM / 32, BB);         // 1024 blocks
    pair_kernel<<<ggrid, 256, 0, stream>>>(pt, ps, wt_out, ws_out, iw, bias, out);
}